// Round 2
// baseline (5339.262 us; speedup 1.0000x reference)
//
#include <hip/hip_runtime.h>
#include <math.h>

// ---- problem constants ----
#define BATCH 32
#define CINCH 256
#define SDIM  256
#define HDIM  64
#define WDIM  64
#define BW    (BATCH*WDIM)     // 2048
#define NGATE (4*SDIM)         // 1024

// ---- workspace layout (in floats) ----
#define XS_OFF   0ull
#define H_OFF    (XS_OFF  + (size_t)HDIM*BW*SDIM)
#define C_OFF    (H_OFF   + (size_t)BW*SDIM)
#define T_OFF    (C_OFF   + (size_t)BW*SDIM)
#define WR_OFF   (T_OFF   + (size_t)BW*SDIM)
#define CB_OFF   (WR_OFF  + (size_t)NGATE*SDIM)
#define WT0_OFF  (CB_OFF  + (size_t)NGATE)
#define WT1_OFF  (WT0_OFF + (size_t)CINCH*SDIM)
#define WST_OFF  (WT1_OFF + (size_t)CINCH*SDIM)
#define WS_TOTAL (WST_OFF + (size_t)SDIM*3*SDIM)

// ------------------------------------------------------------------
// K0: weight prep — transpose everything into coalesced layouts.
// ------------------------------------------------------------------
__global__ void prep_kernel(const float* __restrict__ w_i2s,
                            const float* __restrict__ w_s2s,
                            const float* __restrict__ w_ih,
                            const float* __restrict__ b_ih,
                            const float* __restrict__ b_hh,
                            float* __restrict__ ws) {
  float* wt0 = ws + WT0_OFF;
  float* wt1 = ws + WT1_OFF;
  float* wst = ws + WST_OFF;
  float* w_r = ws + WR_OFF;
  float* cb  = ws + CB_OFF;
  int idx = blockIdx.x * blockDim.x + threadIdx.x;
  int stride = gridDim.x * blockDim.x;

  // i2s taps: [ic][s]; mask: center kept iff (s%3) >= (ic%3); right tap dropped.
  for (int i = idx; i < CINCH * SDIM; i += stride) {
    int ic = i >> 8;
    int s  = i & 255;
    wt0[i] = w_i2s[(s * CINCH + ic) * 3 + 0];
    float cw = w_i2s[(s * CINCH + ic) * 3 + 1];
    wt1[i] = ((s % 3) >= (ic % 3)) ? cw : 0.f;
  }
  // s2s: [u][t][s]
  for (int i = idx; i < SDIM * 3 * SDIM; i += stride) {
    int s  = i & 255;
    int ut = i >> 8;
    int t  = ut % 3;
    int u  = ut / 3;
    wst[i] = w_s2s[(s * SDIM + u) * 3 + t];
  }
  // w_ih reorder: j' = s'*4 + g from row j = g*256 + s'
  for (int i = idx; i < NGATE * SDIM; i += stride) {
    int k  = i & 255;
    int jp = i >> 8;
    int g  = jp & 3;
    int sp = jp >> 2;
    w_r[i] = w_ih[(g * SDIM + sp) * SDIM + k];
  }
  for (int i = idx; i < NGATE; i += stride) {
    int g  = i & 3;
    int sp = i >> 2;
    int j  = g * SDIM + sp;
    cb[i] = b_ih[j] + b_hh[j];
  }
}

// ------------------------------------------------------------------
// K1: masked i2s conv.  One block per (h,b); x[b,:,h,:] staged in LDS.
// ------------------------------------------------------------------
__global__ __launch_bounds__(256) void i2s_kernel(const float* __restrict__ x,
                                                  const float* __restrict__ b_i2s,
                                                  const float* __restrict__ wt0,
                                                  const float* __restrict__ wt1,
                                                  float* __restrict__ xs) {
  __shared__ float xl[CINCH * WDIM];   // 64 KB
  const int b = blockIdx.x & 31;
  const int h = blockIdx.x >> 5;
  const int tid = threadIdx.x;

  const float* xb = x + ((size_t)b * CINCH * HDIM + h) * WDIM;
  for (int i4 = tid; i4 < CINCH * WDIM / 4; i4 += 256) {
    int ic = i4 >> 4;
    int w4 = i4 & 15;
    float4 v = *(const float4*)(xb + (size_t)ic * HDIM * WDIM + w4 * 4);
    *(float4*)(&xl[ic * WDIM + w4 * 4]) = v;
  }
  __syncthreads();

  const int s = tid;
  float acc[WDIM];
#pragma unroll
  for (int w = 0; w < WDIM; ++w) acc[w] = 0.f;

  for (int ic = 0; ic < CINCH; ++ic) {
    float w0 = wt0[ic * SDIM + s];
    float w1 = wt1[ic * SDIM + s];
    const float4* xr4 = (const float4*)(&xl[ic * WDIM]);
    float prev = 0.f;   // x[w-1] at w=0 is zero padding
#pragma unroll
    for (int q = 0; q < 16; ++q) {
      float4 v = xr4[q];
      acc[4 * q + 0] += w0 * prev + w1 * v.x;
      acc[4 * q + 1] += w0 * v.x  + w1 * v.y;
      acc[4 * q + 2] += w0 * v.y  + w1 * v.z;
      acc[4 * q + 3] += w0 * v.z  + w1 * v.w;
      prev = v.w;
    }
  }
  float bias = b_i2s[s];
  float* xsrow = xs + ((size_t)(h * BW + b * WDIM)) * SDIM + s;
#pragma unroll
  for (int w = 0; w < WDIM; ++w) xsrow[(size_t)w * SDIM] = acc[w] + bias;
}

// ------------------------------------------------------------------
// K2: per-step state-to-state conv along BW (crosses batch bounds,
// zero padded at p=-1 and p=2048) + add xs row + b_s2s  -> t_buf.
// ------------------------------------------------------------------
__global__ __launch_bounds__(512) void hc_kernel(const float* __restrict__ h,
                                                 const float* __restrict__ wst,
                                                 const float* __restrict__ xs_step,
                                                 const float* __restrict__ b_s2s,
                                                 float* __restrict__ t_buf) {
  __shared__ float hl[18 * SDIM];   // rows p0-1 .. p0+16
  const int p0 = blockIdx.x * 16;
  const int s0 = blockIdx.y * 128;
  const int tid = threadIdx.x;

  for (int i4 = tid; i4 < 18 * SDIM / 4; i4 += 512) {
    int r  = i4 >> 6;     // / 64
    int c4 = i4 & 63;
    int p  = p0 - 1 + r;
    float4 v;
    if (p < 0 || p >= BW) v = make_float4(0.f, 0.f, 0.f, 0.f);
    else v = *(const float4*)(h + (size_t)p * SDIM + c4 * 4);
    *(float4*)(&hl[r * SDIM + c4 * 4]) = v;
  }
  __syncthreads();

  const int s  = s0 + (tid & 127);
  const int ty = tid >> 7;           // 0..3
  const int base = ty * 4;           // local row pp base; hl[pp] == h[p0-1+pp]
  float a0 = 0.f, a1 = 0.f, a2 = 0.f, a3 = 0.f;

  for (int u = 0; u < SDIM; ++u) {
    float w0 = wst[(u * 3 + 0) * SDIM + s];
    float w1 = wst[(u * 3 + 1) * SDIM + s];
    float w2 = wst[(u * 3 + 2) * SDIM + s];
    float h0 = hl[(base + 0) * SDIM + u];
    float h1 = hl[(base + 1) * SDIM + u];
    float h2 = hl[(base + 2) * SDIM + u];
    float h3 = hl[(base + 3) * SDIM + u];
    float h4 = hl[(base + 4) * SDIM + u];
    float h5 = hl[(base + 5) * SDIM + u];
    a0 += w0 * h0 + w1 * h1 + w2 * h2;
    a1 += w0 * h1 + w1 * h2 + w2 * h3;
    a2 += w0 * h2 + w1 * h3 + w2 * h4;
    a3 += w0 * h3 + w1 * h4 + w2 * h5;
  }
  float bs = b_s2s[s];
  int prow = p0 + base;
  t_buf[(size_t)(prow + 0) * SDIM + s] = a0 + bs + xs_step[(size_t)(prow + 0) * SDIM + s];
  t_buf[(size_t)(prow + 1) * SDIM + s] = a1 + bs + xs_step[(size_t)(prow + 1) * SDIM + s];
  t_buf[(size_t)(prow + 2) * SDIM + s] = a2 + bs + xs_step[(size_t)(prow + 2) * SDIM + s];
  t_buf[(size_t)(prow + 3) * SDIM + s] = a3 + bs + xs_step[(size_t)(prow + 3) * SDIM + s];
}

// ------------------------------------------------------------------
// K3: gates GEMM (2048x1024x256) with gate-interleaved weights +
// fused LSTM epilogue.  BM=64, BN=64, BK=16, 256 threads, 4x4 micro.
// ------------------------------------------------------------------
__device__ __forceinline__ float sigf(float v) { return 1.f / (1.f + expf(-v)); }

__global__ __launch_bounds__(256) void gemm_lstm_kernel(const float* __restrict__ t_buf,
                                                        const float* __restrict__ w_r,
                                                        const float* __restrict__ cb,
                                                        float* __restrict__ h,
                                                        float* __restrict__ c,
                                                        float* __restrict__ out,
                                                        int step) {
  __shared__ float As[16 * 64];   // [k][p]
  __shared__ float Bs[16 * 64];   // [k][j']
  const int p0 = blockIdx.x * 64;
  const int n0 = blockIdx.y * 64;
  const int tid = threadIdx.x;
  const int tx = tid & 15;        // j' group (s' within tile)
  const int ty = tid >> 4;        // p group

  float acc[4][4];
#pragma unroll
  for (int r = 0; r < 4; ++r)
#pragma unroll
    for (int cc = 0; cc < 4; ++cc) acc[r][cc] = 0.f;

  const int lrow = tid >> 2;      // 0..63
  const int lk4  = tid & 3;       // 0..3

  for (int kt = 0; kt < SDIM / 16; ++kt) {
    const int k0 = kt * 16;
    float4 av = *(const float4*)(t_buf + (size_t)(p0 + lrow) * SDIM + k0 + lk4 * 4);
    float4 bv = *(const float4*)(w_r  + (size_t)(n0 + lrow) * SDIM + k0 + lk4 * 4);
    __syncthreads();
    As[(lk4 * 4 + 0) * 64 + lrow] = av.x;
    As[(lk4 * 4 + 1) * 64 + lrow] = av.y;
    As[(lk4 * 4 + 2) * 64 + lrow] = av.z;
    As[(lk4 * 4 + 3) * 64 + lrow] = av.w;
    Bs[(lk4 * 4 + 0) * 64 + lrow] = bv.x;
    Bs[(lk4 * 4 + 1) * 64 + lrow] = bv.y;
    Bs[(lk4 * 4 + 2) * 64 + lrow] = bv.z;
    Bs[(lk4 * 4 + 3) * 64 + lrow] = bv.w;
    __syncthreads();
#pragma unroll
    for (int kk = 0; kk < 16; ++kk) {
      float4 a = *(const float4*)(&As[kk * 64 + ty * 4]);
      float4 b = *(const float4*)(&Bs[kk * 64 + tx * 4]);
      float ar[4] = {a.x, a.y, a.z, a.w};
      float br[4] = {b.x, b.y, b.z, b.w};
#pragma unroll
      for (int r = 0; r < 4; ++r)
#pragma unroll
        for (int cc = 0; cc < 4; ++cc) acc[r][cc] += ar[r] * br[cc];
    }
  }

  // epilogue: cols tx*4..tx*4+3 are gates (i,f,g,o) of s' = n0/4 + tx
  const int sp = (n0 >> 2) + tx;
  float4 cbv = *(const float4*)(&cb[n0 + tx * 4]);
#pragma unroll
  for (int r = 0; r < 4; ++r) {
    int p = p0 + ty * 4 + r;
    float gi = acc[r][0] + cbv.x;
    float gf = acc[r][1] + cbv.y;
    float gg = acc[r][2] + cbv.z;
    float go = acc[r][3] + cbv.w;
    float cold = c[(size_t)p * SDIM + sp];
    float cn = sigf(gf) * cold + sigf(gi) * tanhf(gg);
    float hn = sigf(go) * tanhf(cn);
    c[(size_t)p * SDIM + sp] = cn;
    h[(size_t)p * SDIM + sp] = hn;
    // scrambled output view: out[b][s2][step][w2]
    int bb = p >> 6;
    int w  = p & 63;
    int s2 = (w << 2) | (sp >> 6);
    int w2 = sp & 63;
    out[(((size_t)bb * SDIM + s2) * HDIM + step) * WDIM + w2] = hn;
  }
}

// ------------------------------------------------------------------
extern "C" void kernel_launch(void* const* d_in, const int* in_sizes, int n_in,
                              void* d_out, int out_size, void* d_ws, size_t ws_size,
                              hipStream_t stream) {
  const float* x     = (const float*)d_in[0];
  const float* w_i2s = (const float*)d_in[1];
  const float* b_i2s = (const float*)d_in[2];
  const float* w_s2s = (const float*)d_in[3];
  const float* b_s2s = (const float*)d_in[4];
  const float* w_ih  = (const float*)d_in[5];
  const float* b_ih  = (const float*)d_in[6];
  const float* b_hh  = (const float*)d_in[7];
  float* out = (float*)d_out;
  float* ws  = (float*)d_ws;
  (void)in_sizes; (void)n_in; (void)out_size; (void)ws_size;

  prep_kernel<<<512, 256, 0, stream>>>(w_i2s, w_s2s, w_ih, b_ih, b_hh, ws);
  i2s_kernel<<<HDIM * BATCH, 256, 0, stream>>>(x, b_i2s, ws + WT0_OFF, ws + WT1_OFF,
                                               ws + XS_OFF);
  // zero h and c (contiguous)
  hipMemsetAsync(ws + H_OFF, 0, 2 * (size_t)BW * SDIM * sizeof(float), stream);

  for (int step = 0; step < HDIM; ++step) {
    hc_kernel<<<dim3(BW / 16, 2), 512, 0, stream>>>(
        ws + H_OFF, ws + WST_OFF, ws + XS_OFF + (size_t)step * BW * SDIM, b_s2s,
        ws + T_OFF);
    gemm_lstm_kernel<<<dim3(BW / 64, NGATE / 64), 256, 0, stream>>>(
        ws + T_OFF, ws + WR_OFF, ws + CB_OFF, ws + H_OFF, ws + C_OFF, out, step);
  }
}

// Round 8
// 4486.359 us; speedup vs baseline: 1.1901x; 1.1901x over previous
//
#include <hip/hip_runtime.h>
#include <math.h>

// ---- problem constants ----
#define BATCH 32
#define CINCH 256
#define SDIM  256
#define HDIM  64
#define WDIM  64
#define BW    (BATCH*WDIM)     // 2048
#define NGATE (4*SDIM)         // 1024

// ---- workspace layout (in floats) — byte-identical footprint to the
// Round-2-proven layout; T/WR/CB regions are overlaid with bf16 planes. ----
#define XS_OFF   0ull
#define H_OFF    (XS_OFF  + (size_t)HDIM*BW*SDIM)
#define C_OFF    (H_OFF   + (size_t)BW*SDIM)
#define T_OFF    (C_OFF   + (size_t)BW*SDIM)      // t_hi (1MB) + t_lo (1MB) bf16
#define WR_OFF   (T_OFF   + (size_t)BW*SDIM)      // w_hi (1MB) + w_lo (1MB) bf16, fragment-major
#define CB_OFF   (WR_OFF  + (size_t)NGATE*SDIM)   // cbn[1024] natural order
#define WT0_OFF  (CB_OFF  + (size_t)NGATE)
#define WT1_OFF  (WT0_OFF + (size_t)CINCH*SDIM)
#define WST_OFF  (WT1_OFF + (size_t)CINCH*SDIM)
#define WS_TOTAL (WST_OFF + (size_t)SDIM*3*SDIM)

typedef __attribute__((ext_vector_type(8))) short bf16x8;  // 4 VGPRs, MFMA A/B frag
typedef __attribute__((ext_vector_type(4))) float f32x4;   // MFMA C/D frag

__device__ __forceinline__ ushort f2bf(float f) {   // fp32 -> bf16 RNE
  uint u = __float_as_uint(f);
  u += 0x7fffu + ((u >> 16) & 1u);
  return (ushort)(u >> 16);
}
__device__ __forceinline__ float bf2f(ushort b) {
  return __uint_as_float(((uint)b) << 16);
}
__device__ __forceinline__ float sigf(float v) { return 1.f / (1.f + expf(-v)); }

// ------------------------------------------------------------------
// K0: weight prep.  wt0/wt1 (masked i2s taps), wst (s2s [u][t][s]),
// w_hi/w_lo: w_ih split to bf16 hi/lo in MFMA-B fragment-major order:
//   flat = (((g*16+t16)*8+ks)*64+lane)*8 + r
//   src  = w_ih[g*256 + t16*16+(lane&15)][ks*32 + (lane>>4)*8 + r]
// cbn[j] = b_ih[j] + b_hh[j] (natural order).
// ------------------------------------------------------------------
__global__ void prep_kernel(const float* __restrict__ w_i2s,
                            const float* __restrict__ w_s2s,
                            const float* __restrict__ w_ih,
                            const float* __restrict__ b_ih,
                            const float* __restrict__ b_hh,
                            float* __restrict__ ws) {
  float* wt0 = ws + WT0_OFF;
  float* wt1 = ws + WT1_OFF;
  float* wst = ws + WST_OFF;
  ushort* whi = (ushort*)(ws + WR_OFF);
  ushort* wlo = whi + (size_t)NGATE * SDIM;
  float* cbn = ws + CB_OFF;
  int idx = blockIdx.x * blockDim.x + threadIdx.x;
  int stride = gridDim.x * blockDim.x;

  // i2s taps: [ic][s]; mask: center kept iff (s%3) >= (ic%3); right tap dropped.
  for (int i = idx; i < CINCH * SDIM; i += stride) {
    int ic = i >> 8;
    int s  = i & 255;
    wt0[i] = w_i2s[(s * CINCH + ic) * 3 + 0];
    float cw = w_i2s[(s * CINCH + ic) * 3 + 1];
    wt1[i] = ((s % 3) >= (ic % 3)) ? cw : 0.f;
  }
  // s2s: [u][t][s]  (wst[u*768 + t*256 + s])
  for (int i = idx; i < SDIM * 3 * SDIM; i += stride) {
    int s  = i & 255;
    int ut = i >> 8;
    int t  = ut % 3;
    int u  = ut / 3;
    wst[i] = w_s2s[(s * SDIM + u) * 3 + t];
  }
  // w_ih -> bf16 hi/lo fragment-major
  for (int i = idx; i < NGATE * SDIM; i += stride) {
    int r   = i & 7;
    int ln  = (i >> 3) & 63;
    int ks  = (i >> 9) & 7;
    int gt  = i >> 12;           // g*16 + t16, 0..63
    int g   = gt >> 4;
    int t16 = gt & 15;
    int sp  = t16 * 16 + (ln & 15);
    int k   = ks * 32 + (ln >> 4) * 8 + r;
    float v = w_ih[((size_t)(g * SDIM + sp)) * SDIM + k];
    ushort hi = f2bf(v);
    whi[i] = hi;
    wlo[i] = f2bf(v - bf2f(hi));
  }
  for (int i = idx; i < NGATE; i += stride) cbn[i] = b_ih[i] + b_hh[i];
}

// ------------------------------------------------------------------
// K1: masked i2s conv.  One block per (h,b); x[b,:,h,:] staged in LDS.
// 512 threads: (s, w-half) -> better occupancy at 64 KB LDS/block.
// ------------------------------------------------------------------
__global__ __launch_bounds__(512) void i2s_kernel(const float* __restrict__ x,
                                                  const float* __restrict__ b_i2s,
                                                  const float* __restrict__ wt0,
                                                  const float* __restrict__ wt1,
                                                  float* __restrict__ xs) {
  __shared__ float xl[CINCH * WDIM];   // 64 KB
  const int b = blockIdx.x & 31;
  const int h = blockIdx.x >> 5;
  const int tid = threadIdx.x;

  const float* xb = x + ((size_t)b * CINCH * HDIM + h) * WDIM;
  for (int i4 = tid; i4 < CINCH * WDIM / 4; i4 += 512) {
    int ic = i4 >> 4;
    int w4 = i4 & 15;
    float4 v = *(const float4*)(xb + (size_t)ic * HDIM * WDIM + w4 * 4);
    *(float4*)(&xl[ic * WDIM + w4 * 4]) = v;
  }
  __syncthreads();

  const int s    = tid & 255;
  const int half = tid >> 8;          // 0: w 0..31, 1: w 32..63
  float acc[32];
#pragma unroll
  for (int w = 0; w < 32; ++w) acc[w] = 0.f;

  for (int ic = 0; ic < CINCH; ++ic) {
    float w0 = wt0[ic * SDIM + s];
    float w1 = wt1[ic * SDIM + s];
    const float4* xr4 = (const float4*)(&xl[ic * WDIM + half * 32]);
    float prev = half ? xl[ic * WDIM + 31] : 0.f;
#pragma unroll
    for (int q = 0; q < 8; ++q) {
      float4 v = xr4[q];
      acc[4 * q + 0] += w0 * prev + w1 * v.x;
      acc[4 * q + 1] += w0 * v.x  + w1 * v.y;
      acc[4 * q + 2] += w0 * v.y  + w1 * v.z;
      acc[4 * q + 3] += w0 * v.z  + w1 * v.w;
      prev = v.w;
    }
  }
  float bias = b_i2s[s];
  float* xsrow = xs + ((size_t)(h * BW + b * WDIM) + half * 32) * SDIM + s;
#pragma unroll
  for (int w = 0; w < 32; ++w) xsrow[(size_t)w * SDIM] = acc[w] + bias;
}

// ------------------------------------------------------------------
// K2: phase A — t = conv3(h) + xs_step + b_s2s as tap-sharing GEMM.
// Output written as bf16 hi/lo planes (split for the MFMA gates GEMM).
// ------------------------------------------------------------------
__global__ __launch_bounds__(256) void hc2_kernel(const float* __restrict__ h,
                                                  const float* __restrict__ wst,
                                                  const float* __restrict__ xs_step,
                                                  const float* __restrict__ b_s2s,
                                                  ushort* __restrict__ thi,
                                                  ushort* __restrict__ tlo) {
  __shared__ float hl[32 * 34];      // [u_local][j], j=0..33 <-> h[p0-1+j]
  __shared__ float Bsh[32 * 192];    // [u_local][t][64 s]
  const int p0 = blockIdx.x * 32;
  const int s0 = blockIdx.y * 64;
  const int tid = threadIdx.x;
  const int tx = tid & 15;
  const int ty = tid >> 4;

  float acc[2][4];
#pragma unroll
  for (int r = 0; r < 2; ++r)
#pragma unroll
    for (int cc = 0; cc < 4; ++cc) acc[r][cc] = 0.f;

  for (int kt = 0; kt < 8; ++kt) {
    const int u0 = kt * 32;
    __syncthreads();   // previous tile's reads done before overwrite
    // stage h halo tile: coalesced across u (32 lanes/row)
    for (int i = tid; i < 32 * 34; i += 256) {
      int u_l = i & 31;
      int j   = i >> 5;
      int p   = p0 - 1 + j;
      hl[u_l * 34 + j] = (p < 0 || p >= BW) ? 0.f : h[(size_t)p * SDIM + u0 + u_l];
    }
    // stage weights (vec4)
    for (int i = tid; i < 1536; i += 256) {
      int u_l = i / 48;
      int rem = i - u_l * 48;
      int t   = rem >> 4;
      int s4  = rem & 15;
      float4 v = *(const float4*)(wst + (size_t)(u0 + u_l) * 768 + t * 256 + s0 + s4 * 4);
      *(float4*)(&Bsh[u_l * 192 + t * 64 + s4 * 4]) = v;
    }
    __syncthreads();
#pragma unroll 8
    for (int u = 0; u < 32; ++u) {
      const float* hb = &hl[u * 34 + ty * 2];
      float a[4] = {hb[0], hb[1], hb[2], hb[3]};
      float4 b0 = *(const float4*)(&Bsh[u * 192 + tx * 4]);
      float4 b1 = *(const float4*)(&Bsh[u * 192 + 64 + tx * 4]);
      float4 b2 = *(const float4*)(&Bsh[u * 192 + 128 + tx * 4]);
      float B0[4] = {b0.x, b0.y, b0.z, b0.w};
      float B1[4] = {b1.x, b1.y, b1.z, b1.w};
      float B2[4] = {b2.x, b2.y, b2.z, b2.w};
#pragma unroll
      for (int r = 0; r < 2; ++r)
#pragma unroll
        for (int cc = 0; cc < 4; ++cc)
          acc[r][cc] += B0[cc] * a[r] + B1[cc] * a[r + 1] + B2[cc] * a[r + 2];
    }
  }

  float4 bs4 = *(const float4*)(b_s2s + s0 + tx * 4);
#pragma unroll
  for (int r = 0; r < 2; ++r) {
    int p = p0 + ty * 2 + r;
    float4 xv = *(const float4*)(xs_step + (size_t)p * SDIM + s0 + tx * 4);
    float v0 = acc[r][0] + bs4.x + xv.x;
    float v1 = acc[r][1] + bs4.y + xv.y;
    float v2 = acc[r][2] + bs4.z + xv.z;
    float v3 = acc[r][3] + bs4.w + xv.w;
    ushort h0 = f2bf(v0), h1 = f2bf(v1), h2 = f2bf(v2), h3 = f2bf(v3);
    uint2 ph; ph.x = (uint)h0 | ((uint)h1 << 16); ph.y = (uint)h2 | ((uint)h3 << 16);
    ushort l0 = f2bf(v0 - bf2f(h0)), l1 = f2bf(v1 - bf2f(h1));
    ushort l2 = f2bf(v2 - bf2f(h2)), l3 = f2bf(v3 - bf2f(h3));
    uint2 pl; pl.x = (uint)l0 | ((uint)l1 << 16); pl.y = (uint)l2 | ((uint)l3 << 16);
    size_t off = (size_t)p * SDIM + s0 + tx * 4;
    *(uint2*)(thi + off) = ph;
    *(uint2*)(tlo + off) = pl;
  }
}

// ------------------------------------------------------------------
// K3: gates GEMM via split-bf16 MFMA (16x16x32) + fused LSTM epilogue.
// Block: 256 thr = 4 waves; tile 32p x 64s' x 4 gates; grid (64,4).
// Per wave: 16 s'-cols (t16 = s0/16+wid), 2 p-subtiles, 4 gate accs.
// a*b ~= ahi*bhi + ahi*blo + alo*bhi  (3 MFMAs, fp32 accumulate).
// A frag: lane holds A[l&15][(l>>4)*8+r] (contiguous 8 k — per m92/m97
// ref-checked ladder).  C/D: col=l&15, row=(l>>4)*4+reg (m89-verified).
// ------------------------------------------------------------------
__global__ __launch_bounds__(256) void gates_mfma_kernel(
    const ushort* __restrict__ t_hi, const ushort* __restrict__ t_lo,
    const ushort* __restrict__ w_hi, const ushort* __restrict__ w_lo,
    const float* __restrict__ cbn,
    float* __restrict__ h, float* __restrict__ c,
    float* __restrict__ out, int step) {
  __shared__ ushort Ah[32 * 264];   // rows padded 256->264 (2-way banks = free)
  __shared__ ushort Al[32 * 264];
  const int p0 = blockIdx.x * 32;
  const int s0 = blockIdx.y * 64;
  const int tid  = threadIdx.x;
  const int lane = tid & 63;
  const int wid  = tid >> 6;

  // stage A (t) tiles, hi & lo: 32 rows x 256 k, 16B per thread per iter
  for (int it = 0; it < 4; ++it) {
    int idx8 = it * 256 + tid;        // 8-elem chunk id, 32 chunks/row
    int row  = idx8 >> 5;
    int k8   = (idx8 & 31) * 8;
    size_t goff = (size_t)(p0 + row) * SDIM + k8;
    uint4 vh = *(const uint4*)(t_hi + goff);
    uint4 vl = *(const uint4*)(t_lo + goff);
    *(uint4*)(&Ah[row * 264 + k8]) = vh;
    *(uint4*)(&Al[row * 264 + k8]) = vl;
  }
  __syncthreads();

  const int l15 = lane & 15;
  const int kg  = lane >> 4;          // k-group 0..3
  const int t16 = (s0 >> 4) + wid;    // s'/16 tile

  f32x4 zero = {0.f, 0.f, 0.f, 0.f};
  f32x4 acc[2][4];
#pragma unroll
  for (int sb = 0; sb < 2; ++sb)
#pragma unroll
    for (int g = 0; g < 4; ++g) acc[sb][g] = zero;

#pragma unroll
  for (int ks = 0; ks < 8; ++ks) {
    bf16x8 ah[2], al[2];
#pragma unroll
    for (int sb = 0; sb < 2; ++sb) {
      int ao = (sb * 16 + l15) * 264 + ks * 32 + kg * 8;
      ah[sb] = *(const bf16x8*)(&Ah[ao]);
      al[sb] = *(const bf16x8*)(&Al[ao]);
    }
#pragma unroll
    for (int g = 0; g < 4; ++g) {
      size_t bo = ((((size_t)(g * 16 + t16)) * 8 + ks) * 64 + lane) * 8;
      bf16x8 bh = *(const bf16x8*)(w_hi + bo);
      bf16x8 bl = *(const bf16x8*)(w_lo + bo);
#pragma unroll
      for (int sb = 0; sb < 2; ++sb) {
        acc[sb][g] = __builtin_amdgcn_mfma_f32_16x16x32_bf16(ah[sb], bh, acc[sb][g], 0, 0, 0);
        acc[sb][g] = __builtin_amdgcn_mfma_f32_16x16x32_bf16(ah[sb], bl, acc[sb][g], 0, 0, 0);
        acc[sb][g] = __builtin_amdgcn_mfma_f32_16x16x32_bf16(al[sb], bh, acc[sb][g], 0, 0, 0);
      }
    }
  }

  // epilogue: lane owns (p = p0+sb*16+kg*4+r, s' = s0+wid*16+l15), all 4 gates
  const int sp = s0 + wid * 16 + l15;
  float cbi = cbn[sp], cbf = cbn[256 + sp], cbg = cbn[512 + sp], cbo = cbn[768 + sp];
#pragma unroll
  for (int sb = 0; sb < 2; ++sb) {
#pragma unroll
    for (int r = 0; r < 4; ++r) {
      int p = p0 + sb * 16 + kg * 4 + r;
      float gi = acc[sb][0][r] + cbi;
      float gf = acc[sb][1][r] + cbf;
      float gg = acc[sb][2][r] + cbg;
      float go = acc[sb][3][r] + cbo;
      float cold = c[(size_t)p * SDIM + sp];
      float cn = sigf(gf) * cold + sigf(gi) * tanhf(gg);
      float hn = sigf(go) * tanhf(cn);
      c[(size_t)p * SDIM + sp] = cn;
      h[(size_t)p * SDIM + sp] = hn;
      // scrambled output view: out[b][s2][step][w2]
      int bb = p >> 6;
      int w  = p & 63;
      int s2 = (w << 2) | (sp >> 6);
      int w2 = sp & 63;
      out[(((size_t)bb * SDIM + s2) * HDIM + step) * WDIM + w2] = hn;
    }
  }
}

// ------------------------------------------------------------------
extern "C" void kernel_launch(void* const* d_in, const int* in_sizes, int n_in,
                              void* d_out, int out_size, void* d_ws, size_t ws_size,
                              hipStream_t stream) {
  const float* x     = (const float*)d_in[0];
  const float* w_i2s = (const float*)d_in[1];
  const float* b_i2s = (const float*)d_in[2];
  const float* w_s2s = (const float*)d_in[3];
  const float* b_s2s = (const float*)d_in[4];
  const float* w_ih  = (const float*)d_in[5];
  const float* b_ih  = (const float*)d_in[6];
  const float* b_hh  = (const float*)d_in[7];
  float* out = (float*)d_out;
  float* ws  = (float*)d_ws;
  (void)in_sizes; (void)n_in; (void)out_size; (void)ws_size;

  ushort* thi = (ushort*)(ws + T_OFF);
  ushort* tlo = thi + (size_t)BW * SDIM;
  ushort* whi = (ushort*)(ws + WR_OFF);
  ushort* wlo = whi + (size_t)NGATE * SDIM;

  prep_kernel<<<512, 256, 0, stream>>>(w_i2s, w_s2s, w_ih, b_ih, b_hh, ws);
  i2s_kernel<<<HDIM * BATCH, 512, 0, stream>>>(x, b_i2s, ws + WT0_OFF, ws + WT1_OFF,
                                               ws + XS_OFF);
  // zero h and c (contiguous)
  hipMemsetAsync(ws + H_OFF, 0, 2 * (size_t)BW * SDIM * sizeof(float), stream);

  for (int step = 0; step < HDIM; ++step) {
    hc2_kernel<<<dim3(BW / 32, SDIM / 64), 256, 0, stream>>>(
        ws + H_OFF, ws + WST_OFF, ws + XS_OFF + (size_t)step * BW * SDIM, b_s2s,
        thi, tlo);
    gates_mfma_kernel<<<dim3(BW / 32, SDIM / 64), 256, 0, stream>>>(
        thi, tlo, whi, wlo, ws + CB_OFF, ws + H_OFF, ws + C_OFF, out, step);
  }
}

// Round 11
// 3875.519 us; speedup vs baseline: 1.3777x; 1.1576x over previous
//
#include <hip/hip_runtime.h>
#include <math.h>

// ---- problem constants ----
#define BATCH 32
#define CINCH 256
#define SDIM  256
#define HDIM  64
#define WDIM  64
#define BW    2048
#define NGATE 1024

// ---- workspace layout (float units) ----
// xs hi/lo bf16 planes [64][2048][256]; h hi/lo bf16 DOUBLE-BUFFERED
// (fused kernel reads halo rows + full K while writing own stripe ->
// cross-block race without it); c fp32; W frag-major bf16 hi/lo K=1024;
// cb; i2s taps.  w2b/ws2r alias xs front (consumed before i2s writes xs).
#define XSH_OFF  0ull                          // 16,777,216 fl
#define XSL_OFF  (XSH_OFF + 16777216ull)       // 16,777,216 fl
#define HH0_OFF  (XSL_OFF + 16777216ull)       // 262,144 fl per h plane
#define HL0_OFF  (HH0_OFF + 262144ull)
#define HH1_OFF  (HL0_OFF + 262144ull)
#define HL1_OFF  (HH1_OFF + 262144ull)
#define C_OFF    (HL1_OFF + 262144ull)         // 524,288 fl
#define WFH_OFF  (C_OFF + 524288ull)           // 524,288 fl (1024x1024 bf16)
#define WFL_OFF  (WFH_OFF + 524288ull)         // 524,288 fl
#define CB_OFF   (WFL_OFF + 524288ull)         // 1,024 fl
#define WT0_OFF  (CB_OFF + 1024ull)            // 65,536 fl
#define WT1_OFF  (WT0_OFF + 65536ull)          // 65,536 fl
#define W2B_OFF  XSH_OFF                       // fp32 1024x768 (prep-only)
#define WS2R_OFF (XSH_OFF + 786432ull)         // fp32 256x768 (prep-only)

typedef __attribute__((ext_vector_type(8))) short bf16x8;  // MFMA A/B frag
typedef __attribute__((ext_vector_type(4))) float f32x4;   // MFMA C/D frag

__device__ __forceinline__ ushort f2bf(float f) {   // fp32 -> bf16 RNE
  uint u = __float_as_uint(f);
  u += 0x7fffu + ((u >> 16) & 1u);
  return (ushort)(u >> 16);
}
__device__ __forceinline__ float bf2f(ushort b) {
  return __uint_as_float(((uint)b) << 16);
}
__device__ __forceinline__ float sigf(float v) { return 1.f / (1.f + expf(-v)); }

// ------------------------------------------------------------------
// P0: taps, ws2r reorg, cb (absorbs w_ih@b_s2s), pack w_ih frags (ksg<8).
// Frag layout (round-8 HW-validated): flat=((j16*32+ksg)*64+ln)*8+r,
// j=(j16>>4)*256+(j16&15)*16+(ln&15), k=ksg*32+(ln>>4)*8+r.
// ------------------------------------------------------------------
__global__ void prep0_kernel(const float* __restrict__ w_i2s,
                             const float* __restrict__ w_s2s,
                             const float* __restrict__ w_ih,
                             const float* __restrict__ b_ih,
                             const float* __restrict__ b_hh,
                             const float* __restrict__ b_s2s,
                             float* __restrict__ ws) {
  float* wt0 = ws + WT0_OFF;
  float* wt1 = ws + WT1_OFF;
  float* ws2r = ws + WS2R_OFF;
  float* cb  = ws + CB_OFF;
  ushort* whi = (ushort*)(ws + WFH_OFF);
  ushort* wlo = (ushort*)(ws + WFL_OFF);
  int idx = blockIdx.x * blockDim.x + threadIdx.x;
  int stride = gridDim.x * blockDim.x;

  // i2s taps [ic][s]; center masked by (s%3)>=(ic%3); right tap dropped.
  for (int i = idx; i < CINCH * SDIM; i += stride) {
    int ic = i >> 8;
    int s  = i & 255;
    wt0[i] = w_i2s[(s * CINCH + ic) * 3 + 0];
    float cw = w_i2s[(s * CINCH + ic) * 3 + 1];
    wt1[i] = ((s % 3) >= (ic % 3)) ? cw : 0.f;
  }
  // ws2r[s][t*256+u] = w_s2s[(s*256+u)*3+t]
  for (int i = idx; i < SDIM * 768; i += stride) {
    int s = i / 768;
    int rem = i - s * 768;
    int t = rem >> 8;
    int u = rem & 255;
    ws2r[i] = w_s2s[((size_t)s * SDIM + u) * 3 + t];
  }
  // pack w_ih (k<256 part of W)
  for (int i = idx; i < NGATE * SDIM; i += stride) {
    int r   = i & 7;
    int ln  = (i >> 3) & 63;
    int ks  = (i >> 9) & 7;
    int j16 = i >> 12;
    int j = (j16 >> 4) * 256 + (j16 & 15) * 16 + (ln & 15);
    int k = ks * 32 + (ln >> 4) * 8 + r;
    float v = w_ih[(size_t)j * SDIM + k];
    ushort hi = f2bf(v);
    size_t flat = (((size_t)j16 * 32 + ks) * 64 + ln) * 8 + r;
    whi[flat] = hi;
    wlo[flat] = f2bf(v - bf2f(hi));
  }
  // cb[j] = b_ih + b_hh + sum_s w_ih[j,s]*b_s2s[s]
  for (int j = idx; j < NGATE; j += stride) {
    float a = b_ih[j] + b_hh[j];
    const float* wr = w_ih + (size_t)j * SDIM;
    for (int s = 0; s < SDIM; ++s) a += wr[s] * b_s2s[s];
    cb[j] = a;
  }
}

// ------------------------------------------------------------------
// P1: W2[j][k2] = sum_s w_ih[j,s] * ws2r[s][k2].  1024x768x256 fp32.
// ------------------------------------------------------------------
__global__ __launch_bounds__(256) void prep1_kernel(const float* __restrict__ w_ih,
                                                    const float* __restrict__ ws2r,
                                                    float* __restrict__ w2b) {
  __shared__ float As[16 * 64];   // [k][j_local]
  __shared__ float Bs[16 * 64];   // [k][n_local]
  const int j0 = blockIdx.x * 64;
  const int n0 = blockIdx.y * 64;
  const int tid = threadIdx.x;
  const int tx = tid & 15;
  const int ty = tid >> 4;

  float acc[4][4];
#pragma unroll
  for (int r = 0; r < 4; ++r)
#pragma unroll
    for (int cc = 0; cc < 4; ++cc) acc[r][cc] = 0.f;

  const int lrow = tid >> 2;      // 0..63
  const int lk4  = tid & 3;
  const int bkl  = tid >> 4;      // 0..15
  const int bn4  = tid & 15;

  for (int kt = 0; kt < 16; ++kt) {
    const int k0 = kt * 16;
    float4 av = *(const float4*)(w_ih + (size_t)(j0 + lrow) * SDIM + k0 + lk4 * 4);
    float4 bv = *(const float4*)(ws2r + (size_t)(k0 + bkl) * 768 + n0 + bn4 * 4);
    __syncthreads();
    As[(lk4 * 4 + 0) * 64 + lrow] = av.x;
    As[(lk4 * 4 + 1) * 64 + lrow] = av.y;
    As[(lk4 * 4 + 2) * 64 + lrow] = av.z;
    As[(lk4 * 4 + 3) * 64 + lrow] = av.w;
    *(float4*)(&Bs[bkl * 64 + bn4 * 4]) = bv;
    __syncthreads();
#pragma unroll
    for (int kk = 0; kk < 16; ++kk) {
      float4 a = *(const float4*)(&As[kk * 64 + ty * 4]);
      float4 b = *(const float4*)(&Bs[kk * 64 + tx * 4]);
      float ar[4] = {a.x, a.y, a.z, a.w};
      float br[4] = {b.x, b.y, b.z, b.w};
#pragma unroll
      for (int r = 0; r < 4; ++r)
#pragma unroll
        for (int cc = 0; cc < 4; ++cc) acc[r][cc] += ar[r] * br[cc];
    }
  }
#pragma unroll
  for (int r = 0; r < 4; ++r)
#pragma unroll
    for (int cc = 0; cc < 4; ++cc)
      w2b[(size_t)(j0 + ty * 4 + r) * 768 + n0 + tx * 4 + cc] = acc[r][cc];
}

// ------------------------------------------------------------------
// P2: pack W2 into W frags for ksg in [8,32)  (k2 = tau*256+u).
// ------------------------------------------------------------------
__global__ void prep2_kernel(const float* __restrict__ w2b, float* __restrict__ ws) {
  ushort* whi = (ushort*)(ws + WFH_OFF);
  ushort* wlo = (ushort*)(ws + WFL_OFF);
  int idx = blockIdx.x * blockDim.x + threadIdx.x;
  int stride = gridDim.x * blockDim.x;
  for (int i = idx; i < NGATE * 768; i += stride) {
    int r  = i & 7;
    int ln = (i >> 3) & 63;
    int t1 = i >> 9;
    int ksg8 = t1 % 24;          // 0..23 -> ksg = 8..31
    int j16  = t1 / 24;
    int j  = (j16 >> 4) * 256 + (j16 & 15) * 16 + (ln & 15);
    int k2 = ksg8 * 32 + (ln >> 4) * 8 + r;
    float v = w2b[(size_t)j * 768 + k2];
    ushort hi = f2bf(v);
    size_t flat = (((size_t)j16 * 32 + 8 + ksg8) * 64 + ln) * 8 + r;
    whi[flat] = hi;
    wlo[flat] = f2bf(v - bf2f(hi));
  }
}

// ------------------------------------------------------------------
// K1: masked i2s conv; epilogue writes bf16 hi/lo planes.
// ------------------------------------------------------------------
__global__ __launch_bounds__(512) void i2s_kernel(const float* __restrict__ x,
                                                  const float* __restrict__ b_i2s,
                                                  const float* __restrict__ wt0,
                                                  const float* __restrict__ wt1,
                                                  ushort* __restrict__ xs_hi,
                                                  ushort* __restrict__ xs_lo) {
  __shared__ float xl[CINCH * WDIM];   // 64 KB
  const int b = blockIdx.x & 31;
  const int h = blockIdx.x >> 5;
  const int tid = threadIdx.x;

  const float* xb = x + ((size_t)b * CINCH * HDIM + h) * WDIM;
  for (int i4 = tid; i4 < CINCH * WDIM / 4; i4 += 512) {
    int ic = i4 >> 4;
    int w4 = i4 & 15;
    float4 v = *(const float4*)(xb + (size_t)ic * HDIM * WDIM + w4 * 4);
    *(float4*)(&xl[ic * WDIM + w4 * 4]) = v;
  }
  __syncthreads();

  const int s    = tid & 255;
  const int half = tid >> 8;
  float acc[32];
#pragma unroll
  for (int w = 0; w < 32; ++w) acc[w] = 0.f;

  for (int ic = 0; ic < CINCH; ++ic) {
    float w0 = wt0[ic * SDIM + s];
    float w1 = wt1[ic * SDIM + s];
    const float4* xr4 = (const float4*)(&xl[ic * WDIM + half * 32]);
    float prev = half ? xl[ic * WDIM + 31] : 0.f;
#pragma unroll
    for (int q = 0; q < 8; ++q) {
      float4 v = xr4[q];
      acc[4 * q + 0] += w0 * prev + w1 * v.x;
      acc[4 * q + 1] += w0 * v.x  + w1 * v.y;
      acc[4 * q + 2] += w0 * v.y  + w1 * v.z;
      acc[4 * q + 3] += w0 * v.z  + w1 * v.w;
      prev = v.w;
    }
  }
  float bias = b_i2s[s];
  size_t base = ((size_t)(h * BW + b * WDIM) + half * 32) * SDIM + s;
#pragma unroll
  for (int w = 0; w < 32; ++w) {
    float v = acc[w] + bias;
    ushort hi = f2bf(v);
    xs_hi[base + (size_t)w * SDIM] = hi;
    xs_lo[base + (size_t)w * SDIM] = f2bf(v - bf2f(hi));
  }
}

// ------------------------------------------------------------------
// K2: fused scan step — gates = [xs | h-1 | h0 | h+1](K=1024) x W + cb,
// split-bf16 MFMA (3 products), fused LSTM epilogue.
// Reads h from h_rd (prev step), writes h_wr (next step) — double
// buffered to avoid the cross-block halo race.
// Grid (64,4), 256 thr (4 waves). Tile 32p x 64sp x 4 gates.
// ------------------------------------------------------------------
__global__ __launch_bounds__(256) void gates_fused_kernel(
    const ushort* __restrict__ xs_hi_step, const ushort* __restrict__ xs_lo_step,
    const ushort* __restrict__ h_hi_rd, const ushort* __restrict__ h_lo_rd,
    ushort* __restrict__ h_hi_wr, ushort* __restrict__ h_lo_wr,
    const ushort* __restrict__ w_hi, const ushort* __restrict__ w_lo,
    const float* __restrict__ cbn, float* __restrict__ c,
    float* __restrict__ out, int step) {
  __shared__ ushort Ah[32 * 264];
  __shared__ ushort Al[32 * 264];
  const int p0 = blockIdx.x * 32;
  const int s0 = blockIdx.y * 64;
  const int tid  = threadIdx.x;
  const int lane = tid & 63;
  const int wid  = tid >> 6;
  const int l15 = lane & 15;
  const int kg  = lane >> 4;
  const int t16 = (s0 >> 4) + wid;

  f32x4 zero = {0.f, 0.f, 0.f, 0.f};
  f32x4 acc[2][4];
#pragma unroll
  for (int sb = 0; sb < 2; ++sb)
#pragma unroll
    for (int g = 0; g < 4; ++g) acc[sb][g] = zero;

  for (int tc = 0; tc < 4; ++tc) {
    __syncthreads();   // previous chunk's reads done
    // stage A chunk: 32 rows x 256 k (hi+lo). tc=0: xs; tc>0: h tap tc-1.
#pragma unroll
    for (int it = 0; it < 4; ++it) {
      int idx8 = it * 256 + tid;
      int row  = idx8 >> 5;
      int k8   = (idx8 & 31) * 8;
      uint4 vh, vl;
      if (tc == 0) {
        size_t off = (size_t)(p0 + row) * SDIM + k8;
        vh = *(const uint4*)(xs_hi_step + off);
        vl = *(const uint4*)(xs_lo_step + off);
      } else {
        int pr = p0 + row + tc - 2;          // h row p-1+(tc-1)
        if (pr >= 0 && pr < BW) {
          size_t off = (size_t)pr * SDIM + k8;
          vh = *(const uint4*)(h_hi_rd + off);
          vl = *(const uint4*)(h_lo_rd + off);
        } else {
          vh = make_uint4(0, 0, 0, 0);
          vl = make_uint4(0, 0, 0, 0);
        }
      }
      *(uint4*)(&Ah[row * 264 + k8]) = vh;
      *(uint4*)(&Al[row * 264 + k8]) = vl;
    }
    __syncthreads();
#pragma unroll
    for (int ks = 0; ks < 8; ++ks) {
      bf16x8 ah[2], al[2];
#pragma unroll
      for (int sb = 0; sb < 2; ++sb) {
        int ao = (sb * 16 + l15) * 264 + ks * 32 + kg * 8;
        ah[sb] = *(const bf16x8*)(&Ah[ao]);
        al[sb] = *(const bf16x8*)(&Al[ao]);
      }
      const int ksg = tc * 8 + ks;
#pragma unroll
      for (int g = 0; g < 4; ++g) {
        size_t bo = ((((size_t)(g * 16 + t16)) * 32 + ksg) * 64 + lane) * 8;
        bf16x8 bh = *(const bf16x8*)(w_hi + bo);
        bf16x8 bl = *(const bf16x8*)(w_lo + bo);
#pragma unroll
        for (int sb = 0; sb < 2; ++sb) {
          acc[sb][g] = __builtin_amdgcn_mfma_f32_16x16x32_bf16(ah[sb], bh, acc[sb][g], 0, 0, 0);
          acc[sb][g] = __builtin_amdgcn_mfma_f32_16x16x32_bf16(ah[sb], bl, acc[sb][g], 0, 0, 0);
          acc[sb][g] = __builtin_amdgcn_mfma_f32_16x16x32_bf16(al[sb], bh, acc[sb][g], 0, 0, 0);
        }
      }
    }
  }

  // epilogue: lane owns (p = p0+sb*16+kg*4+r, sp = s0+wid*16+l15)
  const int sp = s0 + wid * 16 + l15;
  float cbi = cbn[sp], cbf = cbn[256 + sp], cbg = cbn[512 + sp], cbo = cbn[768 + sp];
#pragma unroll
  for (int sb = 0; sb < 2; ++sb) {
#pragma unroll
    for (int r = 0; r < 4; ++r) {
      int p = p0 + sb * 16 + kg * 4 + r;
      float gi = acc[sb][0][r] + cbi;
      float gf = acc[sb][1][r] + cbf;
      float gg = acc[sb][2][r] + cbg;
      float go = acc[sb][3][r] + cbo;
      float cold = c[(size_t)p * SDIM + sp];
      float cn = sigf(gf) * cold + sigf(gi) * tanhf(gg);
      float hn = sigf(go) * tanhf(cn);
      c[(size_t)p * SDIM + sp] = cn;
      ushort hh = f2bf(hn);
      h_hi_wr[(size_t)p * SDIM + sp] = hh;
      h_lo_wr[(size_t)p * SDIM + sp] = f2bf(hn - bf2f(hh));
      int bb = p >> 6;
      int w  = p & 63;
      int s2 = (w << 2) | (sp >> 6);
      int w2 = sp & 63;
      out[(((size_t)bb * SDIM + s2) * HDIM + step) * WDIM + w2] = hn;
    }
  }
}

// ------------------------------------------------------------------
extern "C" void kernel_launch(void* const* d_in, const int* in_sizes, int n_in,
                              void* d_out, int out_size, void* d_ws, size_t ws_size,
                              hipStream_t stream) {
  const float* x     = (const float*)d_in[0];
  const float* w_i2s = (const float*)d_in[1];
  const float* b_i2s = (const float*)d_in[2];
  const float* w_s2s = (const float*)d_in[3];
  const float* b_s2s = (const float*)d_in[4];
  const float* w_ih  = (const float*)d_in[5];
  const float* b_ih  = (const float*)d_in[6];
  const float* b_hh  = (const float*)d_in[7];
  float* out = (float*)d_out;
  float* ws  = (float*)d_ws;
  (void)in_sizes; (void)n_in; (void)out_size; (void)ws_size;

  ushort* xs_hi = (ushort*)(ws + XSH_OFF);
  ushort* xs_lo = (ushort*)(ws + XSL_OFF);
  ushort* h_hi0 = (ushort*)(ws + HH0_OFF);
  ushort* h_lo0 = (ushort*)(ws + HL0_OFF);
  ushort* h_hi1 = (ushort*)(ws + HH1_OFF);
  ushort* h_lo1 = (ushort*)(ws + HL1_OFF);
  ushort* w_hi  = (ushort*)(ws + WFH_OFF);
  ushort* w_lo  = (ushort*)(ws + WFL_OFF);
  float*  w2b   = ws + W2B_OFF;   // aliased with xs (consumed before i2s)

  prep0_kernel<<<256, 256, 0, stream>>>(w_i2s, w_s2s, w_ih, b_ih, b_hh, b_s2s, ws);
  prep1_kernel<<<dim3(16, 12), 256, 0, stream>>>(w_ih, ws + WS2R_OFF, w2b);
  prep2_kernel<<<384, 256, 0, stream>>>(w2b, ws);
  i2s_kernel<<<HDIM * BATCH, 512, 0, stream>>>(x, b_i2s, ws + WT0_OFF, ws + WT1_OFF,
                                               xs_hi, xs_lo);
  // zero h (both buffers, hi+lo) and c — contiguous region
  hipMemsetAsync(ws + HH0_OFF, 0, (4ull * 262144 + 524288) * 4, stream);

  for (int step = 0; step < HDIM; ++step) {
    const int par = step & 1;
    gates_fused_kernel<<<dim3(BW / 32, SDIM / 64), 256, 0, stream>>>(
        xs_hi + (size_t)step * BW * SDIM, xs_lo + (size_t)step * BW * SDIM,
        par ? h_hi1 : h_hi0, par ? h_lo1 : h_lo0,     // read (prev step)
        par ? h_hi0 : h_hi1, par ? h_lo0 : h_lo1,     // write (next step)
        w_hi, w_lo, ws + CB_OFF, ws + C_OFF, out, step);
  }
}